// Round 1
// baseline (136.036 us; speedup 1.0000x reference)
//
#include <hip/hip_runtime.h>
#include <cmath>

// ROIAlignV2 multi-level pooler (FPN). fp32 in/out.
// OUT=14, SR=2 -> 28 sample coords per axis per box.
constexpr int OUTD = 14;
constexpr int NBIN = OUTD * OUTD;   // 196
constexpr int NS   = 28;            // OUT*SR
constexpr int CHG  = 32;            // channels per block
constexpr int CTOT = 256;           // total channels

__global__ __launch_bounds__(256) void roi_pool_kernel(
    const float* __restrict__ f0, const float* __restrict__ f1,
    const float* __restrict__ f2, const float* __restrict__ f3,
    const float* __restrict__ boxes, const int* __restrict__ bidx,
    float* __restrict__ out)
{
    const int m  = blockIdx.x;   // box
    const int cg = blockIdx.y;   // channel group

    // ---- box-uniform parameters (computed redundantly per thread; cheap) ----
    const float bx0 = boxes[m*4+0], by0 = boxes[m*4+1];
    const float bx1 = boxes[m*4+2], by1 = boxes[m*4+3];
    const float area = (bx1 - bx0) * (by1 - by0);
    const float size = sqrtf(area);
    float lf = floorf(4.0f + log2f(size / 224.0f + 2.220446049250313e-16f));
    lf = fminf(fmaxf(lf, 2.0f), 5.0f);
    const int L = (int)lf - 2;                       // 0..3
    const float scale = (L == 0) ? 0.25f  : (L == 1) ? 0.125f
                       : (L == 2) ? 0.0625f : 0.03125f;
    const int HW = 256 >> L;                         // square feature map
    const float* feat = (L == 0) ? f0 : (L == 1) ? f1 : (L == 2) ? f2 : f3;
    const int b = bidx[m];

    // ---- per-sample interpolation tables (axis 0 = x, axis 1 = y) ----
    __shared__ int   s_lo[2][NS];
    __shared__ int   s_hi[2][NS];
    __shared__ float s_wl[2][NS];   // (1-l) weight, zeroed if sample invalid
    __shared__ float s_wh[2][NS];   // l weight,     zeroed if sample invalid

    const int t = threadIdx.x;
    if (t < 2 * NS) {
        const int axis = t / NS;       // 0 = x, 1 = y
        const int s    = t % NS;
        const float c0 = (axis ? by0 : bx0) * scale - 0.5f;
        const float c1 = (axis ? by1 : bx1) * scale - 0.5f;
        const float binw = (c1 - c0) * (1.0f / OUTD);
        const float g = (float)(s >> 1) + ((s & 1) ? 0.75f : 0.25f);
        const float p = c0 + g * binw;
        const bool valid = (p > -1.0f) && (p < (float)HW);
        const float pc = fminf(fmaxf(p, 0.0f), (float)(HW - 1));
        const int lo = (int)floorf(pc);
        const int hi = min(lo + 1, HW - 1);
        const float l = pc - (float)lo;
        s_lo[axis][s] = lo;
        s_hi[axis][s] = hi;
        s_wl[axis][s] = valid ? (1.0f - l) : 0.0f;
        s_wh[axis][s] = valid ? l : 0.0f;
    }
    __syncthreads();

    const int W = HW;
    const size_t chan_stride = (size_t)HW * HW;

    // ---- main gather loop: i = c_local*196 + bin, lanes contiguous in bin ----
    for (int i = t; i < CHG * NBIN; i += 256) {
        const int cl  = i / NBIN;
        const int bin = i - cl * NBIN;
        const int ph  = bin / OUTD;
        const int pw  = bin - ph * OUTD;
        const int c   = cg * CHG + cl;
        const float* base = feat + ((size_t)(b * CTOT) + c) * chan_stride;

        float acc = 0.0f;
        #pragma unroll
        for (int jy = 0; jy < 2; ++jy) {
            const int sy = 2 * ph + jy;
            const int   yl = s_lo[1][sy], yh = s_hi[1][sy];
            const float hy = s_wl[1][sy], ly = s_wh[1][sy];
            const float* r0 = base + (size_t)yl * W;
            const float* r1 = base + (size_t)yh * W;
            #pragma unroll
            for (int jx = 0; jx < 2; ++jx) {
                const int sx = 2 * pw + jx;
                const int   xl = s_lo[0][sx], xh = s_hi[0][sx];
                const float hx = s_wl[0][sx], lx = s_wh[0][sx];
                acc += hy * (hx * r0[xl] + lx * r0[xh])
                     + ly * (hx * r1[xl] + lx * r1[xh]);
            }
        }
        out[((size_t)m * CTOT + c) * NBIN + bin] = acc * 0.25f;
    }
}

extern "C" void kernel_launch(void* const* d_in, const int* in_sizes, int n_in,
                              void* d_out, int out_size, void* d_ws, size_t ws_size,
                              hipStream_t stream) {
    const float* f0    = (const float*)d_in[0];
    const float* f1    = (const float*)d_in[1];
    const float* f2    = (const float*)d_in[2];
    const float* f3    = (const float*)d_in[3];
    const float* boxes = (const float*)d_in[4];
    const int*   bidx  = (const int*)d_in[5];
    float* out = (float*)d_out;

    const int M = in_sizes[5];           // number of boxes (batch_idx count)
    dim3 grid(M, CTOT / CHG);            // (256, 8)
    roi_pool_kernel<<<grid, 256, 0, stream>>>(f0, f1, f2, f3, boxes, bidx, out);
}

// Round 2
// 133.931 us; speedup vs baseline: 1.0157x; 1.0157x over previous
//
#include <hip/hip_runtime.h>
#include <cmath>

// ROIAlignV2 multi-level pooler (FPN). fp32 in/out.
// OUT=14, SR=2 -> 28 sample coords per axis per box.
constexpr int OUTD = 14;
constexpr int NBIN = OUTD * OUTD;   // 196
constexpr int NS   = 28;            // OUT*SR
constexpr int CHG  = 32;            // channels per block
constexpr int CPT  = 2;             // channels per thread (c, c+16)
constexpr int CHH  = CHG / CPT;     // 16
constexpr int CTOT = 256;           // total channels

__global__ __launch_bounds__(256) void roi_pool_kernel(
    const float* __restrict__ f0, const float* __restrict__ f1,
    const float* __restrict__ f2, const float* __restrict__ f3,
    const float* __restrict__ boxes, const int* __restrict__ bidx,
    float* __restrict__ out)
{
    const int m  = blockIdx.x;   // box
    const int cg = blockIdx.y;   // channel group

    // ---- box-uniform parameters ----
    const float bx0 = boxes[m*4+0], by0 = boxes[m*4+1];
    const float bx1 = boxes[m*4+2], by1 = boxes[m*4+3];
    const float area = (bx1 - bx0) * (by1 - by0);
    const float size = sqrtf(area);
    float lf = floorf(4.0f + log2f(size / 224.0f + 2.220446049250313e-16f));
    lf = fminf(fmaxf(lf, 2.0f), 5.0f);
    const int L = (int)lf - 2;                       // 0..3
    const float scale = (L == 0) ? 0.25f  : (L == 1) ? 0.125f
                       : (L == 2) ? 0.0625f : 0.03125f;
    const int HW = 256 >> L;                         // square feature map
    const float* feat = (L == 0) ? f0 : (L == 1) ? f1 : (L == 2) ? f2 : f3;
    const int b = bidx[m];

    // ---- per-sample tables, packed 16B: {lo, hi, wl_bits, wh_bits} ----
    // axis 0 = x, axis 1 = y. Validity folded into weights (invalid -> 0).
    __shared__ int4 s_tab[2][NS];

    const int t = threadIdx.x;
    if (t < 2 * NS) {
        const int axis = t / NS;       // 0 = x, 1 = y
        const int s    = t % NS;
        const float c0 = (axis ? by0 : bx0) * scale - 0.5f;
        const float c1 = (axis ? by1 : bx1) * scale - 0.5f;
        const float binw = (c1 - c0) * (1.0f / OUTD);
        const float g = (float)(s >> 1) + ((s & 1) ? 0.75f : 0.25f);
        const float p = c0 + g * binw;
        const bool valid = (p > -1.0f) && (p < (float)HW);
        const float pc = fminf(fmaxf(p, 0.0f), (float)(HW - 1));
        const int lo = (int)floorf(pc);
        const int hi = min(lo + 1, HW - 1);
        const float l = pc - (float)lo;
        const float wl = valid ? (1.0f - l) : 0.0f;
        const float wh = valid ? l : 0.0f;
        int4 e;
        e.x = lo; e.y = hi;
        e.z = __float_as_int(wl); e.w = __float_as_int(wh);
        s_tab[axis][s] = e;
    }
    __syncthreads();

    const int W = HW;
    const size_t chan_stride = (size_t)HW * HW;
    const float* gbase = feat + (size_t)(b * CTOT + cg * CHG) * chan_stride;

    // ---- main loop: i = c_local*196 + bin; lanes contiguous in bin ----
    for (int i = t; i < CHH * NBIN; i += 256) {
        const int cl  = i / NBIN;          // 0..15
        const int bin = i - cl * NBIN;
        const int ph  = bin / OUTD;
        const int pw  = bin - ph * OUTD;

        const int4 ty0 = s_tab[1][2*ph],   ty1 = s_tab[1][2*ph+1];
        const int4 tx0 = s_tab[0][2*pw],   tx1 = s_tab[0][2*pw+1];

        int rows[4]; float wy[4];
        rows[0] = ty0.x * W; wy[0] = __int_as_float(ty0.z);
        rows[1] = ty0.y * W; wy[1] = __int_as_float(ty0.w);
        rows[2] = ty1.x * W; wy[2] = __int_as_float(ty1.z);
        rows[3] = ty1.y * W; wy[3] = __int_as_float(ty1.w);
        int cols[4]; float wx[4];
        cols[0] = tx0.x; wx[0] = __int_as_float(tx0.z);
        cols[1] = tx0.y; wx[1] = __int_as_float(tx0.w);
        cols[2] = tx1.x; wx[2] = __int_as_float(tx1.z);
        cols[3] = tx1.y; wx[3] = __int_as_float(tx1.w);

        const float* b0 = gbase + (size_t)cl * chan_stride;
        const float* b1 = b0 + (size_t)CHH * chan_stride;

        float v0[16], v1[16], w[16];
        #pragma unroll
        for (int k = 0; k < 16; ++k) {
            const int off = rows[k >> 2] + cols[k & 3];
            v0[k] = b0[off];
            v1[k] = b1[off];
            w[k]  = wy[k >> 2] * wx[k & 3];
        }
        float a0 = 0.0f, a1 = 0.0f;
        #pragma unroll
        for (int k = 0; k < 16; ++k) {
            a0 += w[k] * v0[k];
            a1 += w[k] * v1[k];
        }

        const size_t obase = ((size_t)m * CTOT + cg * CHG + cl) * NBIN + bin;
        out[obase] = a0 * 0.25f;
        out[obase + (size_t)CHH * NBIN] = a1 * 0.25f;
    }
}

extern "C" void kernel_launch(void* const* d_in, const int* in_sizes, int n_in,
                              void* d_out, int out_size, void* d_ws, size_t ws_size,
                              hipStream_t stream) {
    const float* f0    = (const float*)d_in[0];
    const float* f1    = (const float*)d_in[1];
    const float* f2    = (const float*)d_in[2];
    const float* f3    = (const float*)d_in[3];
    const float* boxes = (const float*)d_in[4];
    const int*   bidx  = (const int*)d_in[5];
    float* out = (float*)d_out;

    const int M = in_sizes[5];           // number of boxes
    dim3 grid(M, CTOT / CHG);            // (256, 8)
    roi_pool_kernel<<<grid, 256, 0, stream>>>(f0, f1, f2, f3, boxes, bidx, out);
}